// Round 1
// baseline (553.322 us; speedup 1.0000x reference)
//
#include <hip/hip_runtime.h>

// GCN: 3x (GEMM -> CSR aggregate -> bias/relu -> BN-stats), BN folded into next GEMM,
// then segment mean-pool + linear head + softmax.
// Sizes fixed by problem: N=65536 nodes, E=1048576 edges, F=H=64, 64 graphs, 16 classes.

__global__ void k_deg(const int* __restrict__ ei, int E, int* __restrict__ deg) {
    int e = blockIdx.x * blockDim.x + threadIdx.x;
    if (e < E) atomicAdd(&deg[ei[E + e]], 1);
}

__global__ void k_scan1(const int* __restrict__ deg, int* __restrict__ rowptr,
                        int* __restrict__ chunk) {
    __shared__ int s[256];
    int t = threadIdx.x, b = blockIdx.x;
    int v = deg[b * 256 + t];
    s[t] = v;
    __syncthreads();
    for (int o = 1; o < 256; o <<= 1) {
        int x = (t >= o) ? s[t - o] : 0;
        __syncthreads();
        s[t] += x;
        __syncthreads();
    }
    rowptr[b * 256 + t] = s[t] - v;  // local exclusive
    if (t == 255) chunk[b] = s[255];
}

__global__ void k_scan2(int* __restrict__ chunk) {
    __shared__ int s[256];
    int t = threadIdx.x;
    int v = chunk[t];
    s[t] = v;
    __syncthreads();
    for (int o = 1; o < 256; o <<= 1) {
        int x = (t >= o) ? s[t - o] : 0;
        __syncthreads();
        s[t] += x;
        __syncthreads();
    }
    chunk[t] = s[t] - v;  // exclusive
}

__global__ void k_scan3(int* __restrict__ rowptr, const int* __restrict__ chunk,
                        int* __restrict__ cursor, const int* __restrict__ deg,
                        float* __restrict__ dinv, int N, int E) {
    int n = blockIdx.x * 256 + threadIdx.x;
    int r = rowptr[n] + chunk[blockIdx.x];
    rowptr[n] = r;
    cursor[n] = r;
    dinv[n] = rsqrtf((float)(deg[n] + 1));  // +1 self loop
    if (n == 0) rowptr[N] = E;
}

__global__ void k_fill(const int* __restrict__ ei, int E, int* __restrict__ cursor,
                       int* __restrict__ csr) {
    int e = blockIdx.x * blockDim.x + threadIdx.x;
    if (e < E) {
        int s = ei[e], d = ei[E + e];
        int p = atomicAdd(&cursor[d], 1);
        csr[p] = s;
    }
}

// Fold BN(prev layer) into W: Wf[f][j] = rstd[f]*W[f][j]; brow[j] = -sum_f mean[f]*rstd[f]*W[f][j]
__global__ void k_fold(const float* __restrict__ W, const float* __restrict__ mean,
                       const float* __restrict__ rstd, int has_stats,
                       float* __restrict__ Wf, float* __restrict__ brow) {
    __shared__ float sm[64], sr[64];
    int t = threadIdx.x;
    if (t < 64) {
        sm[t] = has_stats ? mean[t] : 0.0f;
        sr[t] = has_stats ? rstd[t] : 1.0f;
    }
    __syncthreads();
    for (int i = t; i < 4096; i += 256) {
        int f = i >> 6;
        Wf[i] = sr[f] * W[i];
    }
    if (t < 64) {
        float acc = 0.0f;
        for (int f = 0; f < 64; ++f) acc += sm[f] * sr[f] * W[f * 64 + t];
        brow[t] = -acc;
    }
}

// y[n][j] = dinv[n] * ( sum_f h[n][f]*Wf[f][j] + brow[j] )
// block 256 threads = 16 rows x 16 col-groups(4 cols each); grid N/16
__global__ void k_gemm(const float* __restrict__ h, const float* __restrict__ Wf,
                       const float* __restrict__ brow, const float* __restrict__ dinv,
                       float* __restrict__ y) {
    __shared__ float Ws[4096];
    __shared__ float hs[16 * 64];
    int t = threadIdx.x;
    int rowBase = blockIdx.x * 16;
    for (int i = t; i < 1024; i += 256)
        ((float4*)Ws)[i] = ((const float4*)Wf)[i];
    ((float4*)hs)[t] = ((const float4*)(h + (size_t)rowBase * 64))[t];
    __syncthreads();
    int rl = t >> 4;   // local row 0..15
    int cg = t & 15;   // col group 0..15 (4 cols each)
    float4 acc;
    acc.x = brow[cg * 4 + 0];
    acc.y = brow[cg * 4 + 1];
    acc.z = brow[cg * 4 + 2];
    acc.w = brow[cg * 4 + 3];
    const float* hrow = hs + rl * 64;
#pragma unroll 8
    for (int f = 0; f < 64; ++f) {
        float hv = hrow[f];
        float4 wv = ((float4*)Ws)[f * 16 + cg];
        acc.x += hv * wv.x;
        acc.y += hv * wv.y;
        acc.z += hv * wv.z;
        acc.w += hv * wv.w;
    }
    float dv = dinv[rowBase + rl];
    acc.x *= dv; acc.y *= dv; acc.z *= dv; acc.w *= dv;
    ((float4*)y)[(size_t)rowBase * 16 + t] = acc;
}

// out[n] = relu?( dinv[n]*(y[n] + sum_{src in csr[n]} y[src]) + bias )
// also accumulates per-block BN partial sums (sum, sumsq) per feature.
template <int RELU>
__global__ void k_agg(const float* __restrict__ y, const int* __restrict__ rowptr,
                      const int* __restrict__ csr, const float* __restrict__ dinv,
                      const float* __restrict__ bias, float* __restrict__ hout,
                      float* __restrict__ partials, int N) {
    int t = threadIdx.x;
    int lane = t & 63;
    int wid = t >> 6;                       // 0..7
    int gwave = blockIdx.x * 8 + wid;       // 0..16383
    float b = bias[lane];
    float ps = 0.0f, pq = 0.0f;
    for (int n = gwave; n < N; n += 16384) {
        int beg = rowptr[n], end = rowptr[n + 1];
        float acc = y[(size_t)n * 64 + lane];
        int k = beg;
        int s_next = (k < end) ? csr[k] : 0;
        while (k < end) {
            int s = s_next;
            ++k;
            s_next = (k < end) ? csr[k] : 0;
            acc += y[(size_t)s * 64 + lane];
        }
        float val = acc * dinv[n] + b;
        if (RELU) val = fmaxf(val, 0.0f);
        hout[(size_t)n * 64 + lane] = val;
        ps += val;
        pq += val * val;
    }
    __shared__ float S[8][64], Q[8][64];
    S[wid][lane] = ps;
    Q[wid][lane] = pq;
    __syncthreads();
    if (t < 64) {
        float s = 0.0f, q = 0.0f;
#pragma unroll
        for (int w = 0; w < 8; ++w) {
            s += S[w][t];
            q += Q[w][t];
        }
        partials[(size_t)blockIdx.x * 128 + t] = s;
        partials[(size_t)blockIdx.x * 128 + 64 + t] = q;
    }
}

// one block per feature: reduce partials -> mean, rstd
__global__ void k_stats(const float* __restrict__ partials, int nblk,
                        float* __restrict__ mean, float* __restrict__ rstd, float invN) {
    __shared__ float sh[256];
    int f = blockIdx.x, t = threadIdx.x;
    float s = 0.0f, q = 0.0f;
    for (int b = t; b < nblk; b += 256) {
        s += partials[(size_t)b * 128 + f];
        q += partials[(size_t)b * 128 + 64 + f];
    }
    sh[t] = s;
    __syncthreads();
    for (int o = 128; o > 0; o >>= 1) {
        if (t < o) sh[t] += sh[t + o];
        __syncthreads();
    }
    float S = sh[0];
    __syncthreads();
    sh[t] = q;
    __syncthreads();
    for (int o = 128; o > 0; o >>= 1) {
        if (t < o) sh[t] += sh[t + o];
        __syncthreads();
    }
    if (t == 0) {
        float Qs = sh[0];
        float m = S * invN;
        float var = Qs * invN - m * m;
        mean[f] = m;
        rstd[f] = rsqrtf(var + 1e-5f);
    }
}

// mean pool with on-the-fly BN of final layer; batch is sorted -> per-run register accum
__global__ void k_pool(const float* __restrict__ h, const int* __restrict__ batch,
                       const float* __restrict__ mean, const float* __restrict__ rstd,
                       float* __restrict__ psum, float* __restrict__ pcnt) {
    int lane = threadIdx.x;
    int base = blockIdx.x * 64;
    float m = mean[lane], r = rstd[lane];
    int cur = batch[base];
    float acc = 0.0f;
    int runlen = 0;
    for (int i = 0; i < 64; ++i) {
        int n = base + i;
        int g = batch[n];
        if (g != cur) {
            atomicAdd(&psum[cur * 64 + lane], acc);
            if (lane == 0) atomicAdd(&pcnt[cur], (float)runlen);
            acc = 0.0f;
            runlen = 0;
            cur = g;
        }
        acc += (h[(size_t)n * 64 + lane] - m) * r;
        runlen++;
    }
    atomicAdd(&psum[cur * 64 + lane], acc);
    if (lane == 0) atomicAdd(&pcnt[cur], (float)runlen);
}

// logits = pooled @ clfW^T + clfb ; softmax over 16 classes. 1 block x 1024 threads.
__global__ void k_head(const float* __restrict__ psum, const float* __restrict__ pcnt,
                       const float* __restrict__ clfW, const float* __restrict__ clfb,
                       float* __restrict__ out) {
    __shared__ float ps[64 * 64];
    __shared__ float wl[16 * 64];
    __shared__ float ci[64];
    int t = threadIdx.x;
    ((float4*)ps)[t] = ((const float4*)psum)[t];
    if (t < 256) ((float4*)wl)[t] = ((const float4*)clfW)[t];
    if (t < 64) ci[t] = 1.0f / fmaxf(pcnt[t], 1.0f);
    __syncthreads();
    int g = t >> 4, c = t & 15;
    float acc = 0.0f;
#pragma unroll 8
    for (int f = 0; f < 64; ++f) acc += ps[g * 64 + f] * wl[c * 64 + f];
    acc = acc * ci[g] + clfb[c];
    float mx = acc;
    for (int o = 1; o < 16; o <<= 1) mx = fmaxf(mx, __shfl_xor(mx, o, 16));
    float e = __expf(acc - mx);
    float s = e;
    for (int o = 1; o < 16; o <<= 1) s += __shfl_xor(s, o, 16);
    out[t] = e / s;
}

extern "C" void kernel_launch(void* const* d_in, const int* in_sizes, int n_in,
                              void* d_out, int out_size, void* d_ws, size_t ws_size,
                              hipStream_t stream) {
    const float* x    = (const float*)d_in[0];
    const int*   ei   = (const int*)d_in[1];
    const int*   bat  = (const int*)d_in[2];
    const float* W0   = (const float*)d_in[3];
    const float* b0   = (const float*)d_in[4];
    const float* W1   = (const float*)d_in[5];
    const float* b1   = (const float*)d_in[6];
    const float* W2   = (const float*)d_in[7];
    const float* b2   = (const float*)d_in[8];
    const float* clfW = (const float*)d_in[9];
    const float* clfb = (const float*)d_in[10];
    float* out = (float*)d_out;

    const int N = in_sizes[0] / 64;   // 65536
    const int E = in_sizes[1] / 2;    // 1048576

    char* w = (char*)d_ws;
    size_t off = 0;
    auto take = [&](size_t bytes) -> void* {
        off = (off + 255) & ~(size_t)255;
        void* p = w + off;
        off += bytes;
        return p;
    };
    int*   deg      = (int*)take((size_t)N * 4);
    int*   rowptr   = (int*)take((size_t)(N + 1) * 4);
    int*   cursor   = (int*)take((size_t)N * 4);
    int*   chunk    = (int*)take(256 * 4);
    float* dinv     = (float*)take((size_t)N * 4);
    int*   csr      = (int*)take((size_t)E * 4);
    float* y        = (float*)take((size_t)N * 64 * 4);
    float* hA       = (float*)take((size_t)N * 64 * 4);
    float* hB       = (float*)take((size_t)N * 64 * 4);
    float* partials = (float*)take((size_t)2048 * 128 * 4);
    float* mean     = (float*)take(256);
    float* rstd     = (float*)take(256);
    float* Wf       = (float*)take(4096 * 4);
    float* brow     = (float*)take(256);
    float* psum     = (float*)take(64 * 64 * 4);
    float* pcnt     = (float*)take(64 * 4);

    hipMemsetAsync(deg, 0, (size_t)N * 4, stream);
    hipMemsetAsync(psum, 0, 64 * 64 * 4, stream);
    hipMemsetAsync(pcnt, 0, 64 * 4, stream);

    int eb = (E + 255) / 256;
    k_deg<<<eb, 256, 0, stream>>>(ei, E, deg);
    k_scan1<<<N / 256, 256, 0, stream>>>(deg, rowptr, chunk);
    k_scan2<<<1, 256, 0, stream>>>(chunk);
    k_scan3<<<N / 256, 256, 0, stream>>>(rowptr, chunk, cursor, deg, dinv, N, E);
    k_fill<<<eb, 256, 0, stream>>>(ei, E, cursor, csr);

    const float invN = 1.0f / (float)N;

    // layer 0 (input x, no BN on input)
    k_fold<<<1, 256, 0, stream>>>(W0, mean, rstd, 0, Wf, brow);
    k_gemm<<<N / 16, 256, 0, stream>>>(x, Wf, brow, dinv, y);
    k_agg<1><<<2048, 512, 0, stream>>>(y, rowptr, csr, dinv, b0, hA, partials, N);
    k_stats<<<64, 256, 0, stream>>>(partials, 2048, mean, rstd, invN);

    // layer 1
    k_fold<<<1, 256, 0, stream>>>(W1, mean, rstd, 1, Wf, brow);
    k_gemm<<<N / 16, 256, 0, stream>>>(hA, Wf, brow, dinv, y);
    k_agg<1><<<2048, 512, 0, stream>>>(y, rowptr, csr, dinv, b1, hB, partials, N);
    k_stats<<<64, 256, 0, stream>>>(partials, 2048, mean, rstd, invN);

    // layer 2 (no relu)
    k_fold<<<1, 256, 0, stream>>>(W2, mean, rstd, 1, Wf, brow);
    k_gemm<<<N / 16, 256, 0, stream>>>(hB, Wf, brow, dinv, y);
    k_agg<0><<<2048, 512, 0, stream>>>(y, rowptr, csr, dinv, b2, hA, partials, N);
    k_stats<<<64, 256, 0, stream>>>(partials, 2048, mean, rstd, invN);

    // pool (applies final BN on the fly) + head
    k_pool<<<N / 64, 64, 0, stream>>>(hA, bat, mean, rstd, psum, pcnt);
    k_head<<<1, 1024, 0, stream>>>(psum, pcnt, clfW, clfb, out);
}

// Round 2
// 368.742 us; speedup vs baseline: 1.5006x; 1.5006x over previous
//
#include <hip/hip_runtime.h>

// GCN: 3x (GEMM -> CSR aggregate -> bias/relu -> BN-stats), BN folded into next GEMM,
// then segment mean-pool + linear head + softmax.
// Sizes fixed by problem: N=65536 nodes, E=1048576 edges, F=H=64, 64 graphs, 16 classes.

__global__ void k_deg(const int* __restrict__ ei, int E, int* __restrict__ deg) {
    int e = blockIdx.x * blockDim.x + threadIdx.x;
    if (e < E) atomicAdd(&deg[ei[E + e]], 1);
}

__global__ void k_scan1(const int* __restrict__ deg, int* __restrict__ rowptr,
                        int* __restrict__ chunk) {
    __shared__ int s[256];
    int t = threadIdx.x, b = blockIdx.x;
    int v = deg[b * 256 + t];
    s[t] = v;
    __syncthreads();
    for (int o = 1; o < 256; o <<= 1) {
        int x = (t >= o) ? s[t - o] : 0;
        __syncthreads();
        s[t] += x;
        __syncthreads();
    }
    rowptr[b * 256 + t] = s[t] - v;  // local exclusive
    if (t == 255) chunk[b] = s[255];
}

__global__ void k_scan2(int* __restrict__ chunk) {
    __shared__ int s[256];
    int t = threadIdx.x;
    int v = chunk[t];
    s[t] = v;
    __syncthreads();
    for (int o = 1; o < 256; o <<= 1) {
        int x = (t >= o) ? s[t - o] : 0;
        __syncthreads();
        s[t] += x;
        __syncthreads();
    }
    chunk[t] = s[t] - v;  // exclusive
}

__global__ void k_scan3(int* __restrict__ rowptr, const int* __restrict__ chunk,
                        int* __restrict__ cursor, const int* __restrict__ deg,
                        float* __restrict__ dinv, int N, int E) {
    int n = blockIdx.x * 256 + threadIdx.x;
    int r = rowptr[n] + chunk[blockIdx.x];
    rowptr[n] = r;
    cursor[n] = r;
    dinv[n] = rsqrtf((float)(deg[n] + 1));  // +1 self loop
    if (n == 0) rowptr[N] = E;
}

__global__ void k_fill(const int* __restrict__ ei, int E, int* __restrict__ cursor,
                       int* __restrict__ csr) {
    int e = blockIdx.x * blockDim.x + threadIdx.x;
    if (e < E) {
        int s = ei[e], d = ei[E + e];
        int p = atomicAdd(&cursor[d], 1);
        csr[p] = s;
    }
}

// Fold BN(prev layer) into W: Wf[f][j] = rstd[f]*W[f][j]; brow[j] = -sum_f mean[f]*rstd[f]*W[f][j]
__global__ void k_fold(const float* __restrict__ W, const float* __restrict__ mean,
                       const float* __restrict__ rstd, int has_stats,
                       float* __restrict__ Wf, float* __restrict__ brow) {
    __shared__ float sm[64], sr[64];
    int t = threadIdx.x;
    if (t < 64) {
        sm[t] = has_stats ? mean[t] : 0.0f;
        sr[t] = has_stats ? rstd[t] : 1.0f;
    }
    __syncthreads();
    for (int i = t; i < 4096; i += 256) {
        int f = i >> 6;
        Wf[i] = sr[f] * W[i];
    }
    if (t < 64) {
        float acc = 0.0f;
        for (int f = 0; f < 64; ++f) acc += sm[f] * sr[f] * W[f * 64 + t];
        brow[t] = -acc;
    }
}

// y[n][j] = dinv[n] * ( sum_f h[n][f]*Wf[f][j] + brow[j] )
// block 256 threads, 64 rows/block; thread = 4x4 output tile (rg=row group, cg=col group)
// hs padded to stride 65 floats: bank = (4*rg_row + f) % 32 -> max 2-way conflict (free)
__global__ void k_gemm(const float* __restrict__ h, const float* __restrict__ Wf,
                       const float* __restrict__ brow, const float* __restrict__ dinv,
                       float* __restrict__ y) {
    __shared__ float Ws[4096];        // [f][c] 64x64
    __shared__ float hs[64 * 65];     // [row][f], stride 65
    int t = threadIdx.x;
    int rowBase = blockIdx.x * 64;
#pragma unroll
    for (int k = 0; k < 4; ++k)
        ((float4*)Ws)[t + k * 256] = ((const float4*)Wf)[t + k * 256];
#pragma unroll
    for (int k = 0; k < 4; ++k) {
        int i = t + k * 256;              // 0..1023 float4s of the h block
        int row = i >> 4, c4 = i & 15;
        float4 v = ((const float4*)(h + (size_t)rowBase * 64))[i];
        float* dst = &hs[row * 65 + c4 * 4];
        dst[0] = v.x; dst[1] = v.y; dst[2] = v.z; dst[3] = v.w;
    }
    __syncthreads();
    int rg = t >> 4;   // 0..15, rows rg*4..rg*4+3
    int cg = t & 15;   // 0..15, cols cg*4..cg*4+3
    float4 a0, a1, a2, a3;
    {
        float bx = brow[cg * 4 + 0], by = brow[cg * 4 + 1];
        float bz = brow[cg * 4 + 2], bw = brow[cg * 4 + 3];
        a0 = {bx, by, bz, bw}; a1 = a0; a2 = a0; a3 = a0;
    }
    const float* h0 = &hs[(rg * 4 + 0) * 65];
    const float* h1 = &hs[(rg * 4 + 1) * 65];
    const float* h2 = &hs[(rg * 4 + 2) * 65];
    const float* h3 = &hs[(rg * 4 + 3) * 65];
#pragma unroll 4
    for (int f = 0; f < 64; ++f) {
        float4 wv = ((float4*)Ws)[f * 16 + cg];
        float v0 = h0[f], v1 = h1[f], v2 = h2[f], v3 = h3[f];
        a0.x += v0 * wv.x; a0.y += v0 * wv.y; a0.z += v0 * wv.z; a0.w += v0 * wv.w;
        a1.x += v1 * wv.x; a1.y += v1 * wv.y; a1.z += v1 * wv.z; a1.w += v1 * wv.w;
        a2.x += v2 * wv.x; a2.y += v2 * wv.y; a2.z += v2 * wv.z; a2.w += v2 * wv.w;
        a3.x += v3 * wv.x; a3.y += v3 * wv.y; a3.z += v3 * wv.z; a3.w += v3 * wv.w;
    }
    float d0 = dinv[rowBase + rg * 4 + 0];
    float d1 = dinv[rowBase + rg * 4 + 1];
    float d2 = dinv[rowBase + rg * 4 + 2];
    float d3 = dinv[rowBase + rg * 4 + 3];
    a0.x *= d0; a0.y *= d0; a0.z *= d0; a0.w *= d0;
    a1.x *= d1; a1.y *= d1; a1.z *= d1; a1.w *= d1;
    a2.x *= d2; a2.y *= d2; a2.z *= d2; a2.w *= d2;
    a3.x *= d3; a3.y *= d3; a3.z *= d3; a3.w *= d3;
    float4* y4 = (float4*)y;
    size_t ob = (size_t)(rowBase + rg * 4) * 16 + cg;
    y4[ob + 0]  = a0;
    y4[ob + 16] = a1;
    y4[ob + 32] = a2;
    y4[ob + 48] = a3;
}

// out[n] = relu?( dinv[n]*(y[n] + sum_{src in csr[n]} y[src]) + bias )
// 8-wide unrolled gather with clamped-index predication: 8 loads in flight per wave.
// also accumulates per-block BN partial sums (sum, sumsq) per feature.
template <int RELU>
__global__ void k_agg(const float* __restrict__ y, const int* __restrict__ rowptr,
                      const int* __restrict__ csr, const float* __restrict__ dinv,
                      const float* __restrict__ bias, float* __restrict__ hout,
                      float* __restrict__ partials, int N) {
    int t = threadIdx.x;
    int lane = t & 63;
    int wid = t >> 6;                       // 0..7
    int gwave = blockIdx.x * 8 + wid;       // 0..16383
    float b = bias[lane];
    float ps = 0.0f, pq = 0.0f;
    for (int n = gwave; n < N; n += 16384) {
        int beg = rowptr[n], end = rowptr[n + 1];
        float a0 = y[(size_t)n * 64 + lane];
        float a1 = 0.0f, a2 = 0.0f, a3 = 0.0f;
        float a4 = 0.0f, a5 = 0.0f, a6 = 0.0f, a7 = 0.0f;
        for (int k = beg; k < end; k += 8) {
            int e1 = min(k + 1, end - 1), e2 = min(k + 2, end - 1);
            int e3 = min(k + 3, end - 1), e4 = min(k + 4, end - 1);
            int e5 = min(k + 5, end - 1), e6 = min(k + 6, end - 1);
            int e7 = min(k + 7, end - 1);
            int s0 = csr[k],  s1 = csr[e1], s2 = csr[e2], s3 = csr[e3];
            int s4 = csr[e4], s5 = csr[e5], s6 = csr[e6], s7 = csr[e7];
            float v0 = y[(size_t)s0 * 64 + lane];
            float v1 = y[(size_t)s1 * 64 + lane];
            float v2 = y[(size_t)s2 * 64 + lane];
            float v3 = y[(size_t)s3 * 64 + lane];
            float v4 = y[(size_t)s4 * 64 + lane];
            float v5 = y[(size_t)s5 * 64 + lane];
            float v6 = y[(size_t)s6 * 64 + lane];
            float v7 = y[(size_t)s7 * 64 + lane];
            a0 += v0;
            a1 += (k + 1 < end) ? v1 : 0.0f;
            a2 += (k + 2 < end) ? v2 : 0.0f;
            a3 += (k + 3 < end) ? v3 : 0.0f;
            a4 += (k + 4 < end) ? v4 : 0.0f;
            a5 += (k + 5 < end) ? v5 : 0.0f;
            a6 += (k + 6 < end) ? v6 : 0.0f;
            a7 += (k + 7 < end) ? v7 : 0.0f;
        }
        float acc = ((a0 + a1) + (a2 + a3)) + ((a4 + a5) + (a6 + a7));
        float val = acc * dinv[n] + b;
        if (RELU) val = fmaxf(val, 0.0f);
        hout[(size_t)n * 64 + lane] = val;
        ps += val;
        pq += val * val;
    }
    __shared__ float S[8][64], Q[8][64];
    S[wid][lane] = ps;
    Q[wid][lane] = pq;
    __syncthreads();
    if (t < 64) {
        float s = 0.0f, q = 0.0f;
#pragma unroll
        for (int w = 0; w < 8; ++w) {
            s += S[w][t];
            q += Q[w][t];
        }
        partials[(size_t)blockIdx.x * 128 + t] = s;
        partials[(size_t)blockIdx.x * 128 + 64 + t] = q;
    }
}

// one block per feature: reduce partials -> mean, rstd
__global__ void k_stats(const float* __restrict__ partials, int nblk,
                        float* __restrict__ mean, float* __restrict__ rstd, float invN) {
    __shared__ float sh[256];
    int f = blockIdx.x, t = threadIdx.x;
    float s = 0.0f, q = 0.0f;
    for (int b = t; b < nblk; b += 256) {
        s += partials[(size_t)b * 128 + f];
        q += partials[(size_t)b * 128 + 64 + f];
    }
    sh[t] = s;
    __syncthreads();
    for (int o = 128; o > 0; o >>= 1) {
        if (t < o) sh[t] += sh[t + o];
        __syncthreads();
    }
    float S = sh[0];
    __syncthreads();
    sh[t] = q;
    __syncthreads();
    for (int o = 128; o > 0; o >>= 1) {
        if (t < o) sh[t] += sh[t + o];
        __syncthreads();
    }
    if (t == 0) {
        float Qs = sh[0];
        float m = S * invN;
        float var = Qs * invN - m * m;
        mean[f] = m;
        rstd[f] = rsqrtf(var + 1e-5f);
    }
}

// mean pool with on-the-fly BN of final layer; batch is sorted -> per-run register accum
__global__ void k_pool(const float* __restrict__ h, const int* __restrict__ batch,
                       const float* __restrict__ mean, const float* __restrict__ rstd,
                       float* __restrict__ psum, float* __restrict__ pcnt) {
    int lane = threadIdx.x;
    int base = blockIdx.x * 64;
    float m = mean[lane], r = rstd[lane];
    int cur = batch[base];
    float acc = 0.0f;
    int runlen = 0;
    for (int i = 0; i < 64; ++i) {
        int n = base + i;
        int g = batch[n];
        if (g != cur) {
            atomicAdd(&psum[cur * 64 + lane], acc);
            if (lane == 0) atomicAdd(&pcnt[cur], (float)runlen);
            acc = 0.0f;
            runlen = 0;
            cur = g;
        }
        acc += (h[(size_t)n * 64 + lane] - m) * r;
        runlen++;
    }
    atomicAdd(&psum[cur * 64 + lane], acc);
    if (lane == 0) atomicAdd(&pcnt[cur], (float)runlen);
}

// logits = pooled @ clfW^T + clfb ; softmax over 16 classes. 1 block x 1024 threads.
__global__ void k_head(const float* __restrict__ psum, const float* __restrict__ pcnt,
                       const float* __restrict__ clfW, const float* __restrict__ clfb,
                       float* __restrict__ out) {
    __shared__ float ps[64 * 64];
    __shared__ float wl[16 * 64];
    __shared__ float ci[64];
    int t = threadIdx.x;
    ((float4*)ps)[t] = ((const float4*)psum)[t];
    if (t < 256) ((float4*)wl)[t] = ((const float4*)clfW)[t];
    if (t < 64) ci[t] = 1.0f / fmaxf(pcnt[t], 1.0f);
    __syncthreads();
    int g = t >> 4, c = t & 15;
    float acc = 0.0f;
#pragma unroll 8
    for (int f = 0; f < 64; ++f) acc += ps[g * 64 + f] * wl[c * 64 + f];
    acc = acc * ci[g] + clfb[c];
    float mx = acc;
    for (int o = 1; o < 16; o <<= 1) mx = fmaxf(mx, __shfl_xor(mx, o, 16));
    float e = __expf(acc - mx);
    float s = e;
    for (int o = 1; o < 16; o <<= 1) s += __shfl_xor(s, o, 16);
    out[t] = e / s;
}

extern "C" void kernel_launch(void* const* d_in, const int* in_sizes, int n_in,
                              void* d_out, int out_size, void* d_ws, size_t ws_size,
                              hipStream_t stream) {
    const float* x    = (const float*)d_in[0];
    const int*   ei   = (const int*)d_in[1];
    const int*   bat  = (const int*)d_in[2];
    const float* W0   = (const float*)d_in[3];
    const float* b0   = (const float*)d_in[4];
    const float* W1   = (const float*)d_in[5];
    const float* b1   = (const float*)d_in[6];
    const float* W2   = (const float*)d_in[7];
    const float* b2   = (const float*)d_in[8];
    const float* clfW = (const float*)d_in[9];
    const float* clfb = (const float*)d_in[10];
    float* out = (float*)d_out;

    const int N = in_sizes[0] / 64;   // 65536
    const int E = in_sizes[1] / 2;    // 1048576

    char* w = (char*)d_ws;
    size_t off = 0;
    auto take = [&](size_t bytes) -> void* {
        off = (off + 255) & ~(size_t)255;
        void* p = w + off;
        off += bytes;
        return p;
    };
    int*   deg      = (int*)take((size_t)N * 4);
    int*   rowptr   = (int*)take((size_t)(N + 1) * 4);
    int*   cursor   = (int*)take((size_t)N * 4);
    int*   chunk    = (int*)take(256 * 4);
    float* dinv     = (float*)take((size_t)N * 4);
    int*   csr      = (int*)take((size_t)E * 4);
    float* y        = (float*)take((size_t)N * 64 * 4);
    float* hA       = (float*)take((size_t)N * 64 * 4);
    float* hB       = (float*)take((size_t)N * 64 * 4);
    float* partials = (float*)take((size_t)2048 * 128 * 4);
    float* mean     = (float*)take(256);
    float* rstd     = (float*)take(256);
    float* Wf       = (float*)take(4096 * 4);
    float* brow     = (float*)take(256);
    float* psum     = (float*)take(64 * 64 * 4);
    float* pcnt     = (float*)take(64 * 4);

    hipMemsetAsync(deg, 0, (size_t)N * 4, stream);
    hipMemsetAsync(psum, 0, 64 * 64 * 4, stream);
    hipMemsetAsync(pcnt, 0, 64 * 4, stream);

    int eb = (E + 255) / 256;
    k_deg<<<eb, 256, 0, stream>>>(ei, E, deg);
    k_scan1<<<N / 256, 256, 0, stream>>>(deg, rowptr, chunk);
    k_scan2<<<1, 256, 0, stream>>>(chunk);
    k_scan3<<<N / 256, 256, 0, stream>>>(rowptr, chunk, cursor, deg, dinv, N, E);
    k_fill<<<eb, 256, 0, stream>>>(ei, E, cursor, csr);

    const float invN = 1.0f / (float)N;

    // layer 0 (input x, no BN on input)
    k_fold<<<1, 256, 0, stream>>>(W0, mean, rstd, 0, Wf, brow);
    k_gemm<<<N / 64, 256, 0, stream>>>(x, Wf, brow, dinv, y);
    k_agg<1><<<2048, 512, 0, stream>>>(y, rowptr, csr, dinv, b0, hA, partials, N);
    k_stats<<<64, 256, 0, stream>>>(partials, 2048, mean, rstd, invN);

    // layer 1
    k_fold<<<1, 256, 0, stream>>>(W1, mean, rstd, 1, Wf, brow);
    k_gemm<<<N / 64, 256, 0, stream>>>(hA, Wf, brow, dinv, y);
    k_agg<1><<<2048, 512, 0, stream>>>(y, rowptr, csr, dinv, b1, hB, partials, N);
    k_stats<<<64, 256, 0, stream>>>(partials, 2048, mean, rstd, invN);

    // layer 2 (no relu)
    k_fold<<<1, 256, 0, stream>>>(W2, mean, rstd, 1, Wf, brow);
    k_gemm<<<N / 64, 256, 0, stream>>>(hB, Wf, brow, dinv, y);
    k_agg<0><<<2048, 512, 0, stream>>>(y, rowptr, csr, dinv, b2, hA, partials, N);
    k_stats<<<64, 256, 0, stream>>>(partials, 2048, mean, rstd, invN);

    // pool (applies final BN on the fly) + head
    k_pool<<<N / 64, 64, 0, stream>>>(hA, bat, mean, rstd, psum, pcnt);
    k_head<<<1, 1024, 0, stream>>>(psum, pcnt, clfW, clfb, out);
}